// Round 13
// baseline (155.566 us; speedup 1.0000x reference)
//
#include <hip/hip_runtime.h>
#include <hip/hip_bf16.h>
#include <stdint.h>
#include <stddef.h>

#define BATCH 4096
#define INF   1024
#define OUTF  1024
#define KDIM  8192            // 1024 in-features * 8 spline bases
#define KS    4               // split-K factor
#define KSL   (KDIM / KS)     // 2048 per slice
#define BK    64
#define NT    (KSL / BK)      // 32 K-tiles per block

typedef __attribute__((ext_vector_type(8)))  short           short8;
typedef __attribute__((ext_vector_type(8)))  unsigned short  ushort8;
typedef __attribute__((ext_vector_type(4)))  float           f32x4;

__device__ constexpr float knot(int j) { return (float)(j - 3) * 0.4f - 1.0f; }

// B-spline bases for one x: 8 bf16 packed in 16 B (identical math to reference).
__device__ __forceinline__ ushort8 bases8(float xv) {
    float b[11];
#pragma unroll
    for (int j = 0; j < 11; ++j)
        b[j] = (xv >= knot(j) && xv < knot(j + 1)) ? 1.0f : 0.0f;
#pragma unroll
    for (int k = 1; k <= 3; ++k) {
#pragma unroll
        for (int j = 0; j + k < 11; ++j) {
            float left  = (xv - knot(j))         * (1.0f / (knot(j + k)     - knot(j)));
            float right = (knot(j + k + 1) - xv) * (1.0f / (knot(j + k + 1) - knot(j + 1)));
            b[j] = left * b[j] + right * b[j + 1];
        }
    }
    union { ushort8 v; unsigned short u[8]; } pk;
#pragma unroll
    for (int g = 0; g < 8; ++g) {
        __hip_bfloat16 h = __float2bfloat16(b[g]);
        pk.u[g] = *reinterpret_cast<unsigned short*>(&h);
    }
    return pk.v;
}

// ---------------------------------------------------------------------------
// Kernel 1: weight fp32 -> bf16 (B^T row-major over k = i*8+g already).
// ---------------------------------------------------------------------------
__global__ __launch_bounds__(256) void kan_wconv(const f32x4* __restrict__ w,
                                                 short8* __restrict__ Wb) {
    size_t idx = (size_t)blockIdx.x * 256 + threadIdx.x;
    f32x4 a = w[idx * 2];
    f32x4 c = w[idx * 2 + 1];
    float t[8] = {a[0], a[1], a[2], a[3], c[0], c[1], c[2], c[3]};
    union { short8 v; unsigned short u[8]; } pk;
#pragma unroll
    for (int g = 0; g < 8; ++g) {
        __hip_bfloat16 h = __float2bfloat16(t[g]);
        pk.u[g] = *reinterpret_cast<unsigned short*>(&h);
    }
    Wb[idx] = pk.v;
}

// ---------------------------------------------------------------------------
// Kernel 2: FUSED bases + bf16 GEMM. 256x256 tile, BK=64, split-K=4,
// double-buffer (128 KiB). 1024 threads = 16 waves (4M x 4N, 64x64/wave),
// mfma_f32_16x16x32_bf16, zero-conflict fragment pattern (r10/r11-verified).
// A is GENERATED per tile: each thread loads 2 x-values, computes bases,
// ds_write_b128 into the swizzled A buffer (2-way bank aliasing = free).
// B staged via global_load_lds as in r11. One vmcnt(0)+lgkmcnt(0)+barrier
// per K-tile. mode 0: bf16 split-K partials; mode 1: fp32 atomic fallback.
// ---------------------------------------------------------------------------
__device__ __forceinline__ void gload16(const void* g, void* l) {
    __builtin_amdgcn_global_load_lds((const __attribute__((address_space(1))) void*)g,
                                     (__attribute__((address_space(3))) void*)l,
                                     16, 0, 0);
}

#define MFMA(a, b, c) __builtin_amdgcn_mfma_f32_16x16x32_bf16((a), (b), (c), 0, 0, 0)

__global__ __launch_bounds__(1024, 1) void kan_gemm(const float* __restrict__ x,
                                                    const __hip_bfloat16* __restrict__ Bt,
                                                    __hip_bfloat16* __restrict__ Pb,
                                                    float* __restrict__ outC,
                                                    int mode) {
    __shared__ __hip_bfloat16 sA[2][256 * 64];   // 64 KiB
    __shared__ __hip_bfloat16 sB[2][256 * 64];   // 64 KiB

    const int tid  = threadIdx.x;
    const int orig = blockIdx.x;
    const int sb   = (orig & 7) * 32 + (orig >> 3);   // XCD chunk swizzle (256%8==0)
    const int bm   = sb >> 4;            // 0..15
    const int bn   = (sb >> 2) & 3;      // 0..3
    const int ks   = sb & 3;             // 0..3
    const int m0   = bm << 8;
    const int n0   = bn << 8;
    const int k0   = ks * KSL;

    // --- B staging (r11-identical): rows (t>>3)+r*128, 16B slot (t&7); linear
    // dest; source col pre-swizzled: LDS[row][s] = G[row][s ^ (row&7)].
    const int srow = tid >> 3;                                // 0..127
    const int scol = (((tid & 7) ^ (srow & 7)) << 3);         // elems
    const __hip_bfloat16* gB = Bt + (size_t)(n0 + srow) * KDIM + k0 + scol;
    const int t8 = tid * 8;

#define GLB(buf, kt, r) gload16(gB + (size_t)(kt) * BK + (size_t)((r) * 128) * KDIM, \
                                &sB[buf][(r) * 8192 + t8])

    // --- A generation: thread -> row (tid>>2), ii-pair ((tid&3)*2, +1).
    // k = i*8+g ; per-tile i-base = k0/8 + t*8. Writes swizzled slots.
    const int grow = tid >> 2;                    // 0..255
    const int gii  = (tid & 3) << 1;              // 0,2,4,6
    const int grx  = grow & 7;
    const float* gx = x + (size_t)(m0 + grow) * INF + (k0 >> 3) + gii;
    __hip_bfloat16* aRow = &sA[0][0] + grow * 64;             // + buf*16384

#define GENA(buf, kt) do {                                                      \
        float2 xv = *reinterpret_cast<const float2*>(gx + (size_t)(kt) * 8);    \
        ushort8 p0 = bases8(xv.x);                                              \
        ushort8 p1 = bases8(xv.y);                                              \
        *reinterpret_cast<ushort8*>(aRow + (buf) * 16384 + (((gii    ) ^ grx) << 3)) = p0; \
        *reinterpret_cast<ushort8*>(aRow + (buf) * 16384 + (((gii + 1) ^ grx) << 3)) = p1; \
    } while (0)

    // compute: wave w -> rows [(w>>2)*64,+64), cols [(w&3)*64,+64)
    const int w    = tid >> 6;
    const int lane = tid & 63;
    const int wr   = w >> 2;             // 0..3
    const int wc   = w & 3;              // 0..3
    const int lr   = lane & 15;
    const int lk   = lane >> 4;          // 0..3
    const int ar0  = (wr << 6) + lr;     // + fi*16
    const int br0  = (wc << 6) + lr;     // + fj*16
    const int rx   = lr & 7;             // read-side XOR (row&7)

    f32x4 acc[4][4];
#pragma unroll
    for (int i = 0; i < 4; ++i)
#pragma unroll
        for (int j = 0; j < 4; ++j)
            acc[i][j] = (f32x4){0.0f, 0.0f, 0.0f, 0.0f};

    // --- prologue: stage B tile 0 + generate A tile 0 into buf0 ---
    GLB(0, 0, 0); GLB(0, 0, 1);
    GENA(0, 0);
    asm volatile("s_waitcnt vmcnt(0) lgkmcnt(0)" ::: "memory");
    __builtin_amdgcn_s_barrier();

#pragma unroll 1
    for (int t = 0; t < NT; ++t) {
        const int buf = t & 1;
        const __hip_bfloat16* tA = &sA[buf][0];
        const __hip_bfloat16* tB = &sB[buf][0];

        // stage tile t+1 into the other buffer: B gloads issue first, then
        // A-gen VALU (free to interleave with the MFMA body below).
        if (t + 1 < NT) {
            GLB(buf ^ 1, t + 1, 0); GLB(buf ^ 1, t + 1, 1);
            GENA(buf ^ 1, t + 1);
        }

        // epoch body: 2 kk steps; per step 8 ds_read_b128 + 16 MFMA(16x16x32).
        // phys slot = (4kk+lk) ^ (lr&7) -> 0 conflicts (r10/r11-measured).
#pragma unroll
        for (int kk = 0; kk < 2; ++kk) {
            const int ph = (((kk << 2) | lk) ^ rx) << 3;   // elem offset in row
            short8 af[4], bf[4];
#pragma unroll
            for (int fi = 0; fi < 4; ++fi)
                af[fi] = *reinterpret_cast<const short8*>(tA + (ar0 + fi * 16) * BK + ph);
#pragma unroll
            for (int fj = 0; fj < 4; ++fj)
                bf[fj] = *reinterpret_cast<const short8*>(tB + (br0 + fj * 16) * BK + ph);
#pragma unroll
            for (int fi = 0; fi < 4; ++fi)
#pragma unroll
                for (int fj = 0; fj < 4; ++fj)
                    acc[fi][fj] = MFMA(af[fi], bf[fj], acc[fi][fj]);
        }

        // --- epoch boundary: B staging landed + A ds_writes committed ---
        asm volatile("s_waitcnt vmcnt(0) lgkmcnt(0)" ::: "memory");
        __builtin_amdgcn_s_barrier();
    }
#undef GLB
#undef GENA

    // --- epilogue: 16x16 C/D layout: col = lane&15, row = (lane>>4)*4 + reg ---
    if (mode == 0) {
        __hip_bfloat16* dst = Pb + (size_t)ks * BATCH * OUTF;
#pragma unroll
        for (int fi = 0; fi < 4; ++fi) {
#pragma unroll
            for (int fj = 0; fj < 4; ++fj) {
                __hip_bfloat16* cp = dst
                    + (size_t)(m0 + (wr << 6) + fi * 16 + lk * 4) * OUTF
                    + (n0 + (wc << 6) + fj * 16 + lr);
#pragma unroll
                for (int r = 0; r < 4; ++r)
                    cp[(size_t)r * OUTF] = __float2bfloat16(acc[fi][fj][r]);
            }
        }
    } else {
#pragma unroll
        for (int fi = 0; fi < 4; ++fi) {
#pragma unroll
            for (int fj = 0; fj < 4; ++fj) {
                float* cp = outC + (size_t)(m0 + (wr << 6) + fi * 16 + lk * 4) * OUTF
                                 + (n0 + (wc << 6) + fj * 16 + lr);
#pragma unroll
                for (int r = 0; r < 4; ++r)
                    atomicAdd(cp + (size_t)r * OUTF, acc[fi][fj][r]);
            }
        }
    }
}

// ---------------------------------------------------------------------------
// Kernel 3: split-K reduce  out = sum of 4 bf16 partials (fp32 accumulate).
// ---------------------------------------------------------------------------
__global__ __launch_bounds__(256) void kan_reduce(const ushort8* __restrict__ Pb,
                                                  f32x4* __restrict__ out) {
    size_t i = (size_t)blockIdx.x * 256 + threadIdx.x;   // per 8 elems
    const size_t stride = (size_t)BATCH * OUTF / 8;
    ushort8 p0 = Pb[i];
    ushort8 p1 = Pb[i + stride];
    ushort8 p2 = Pb[i + 2 * stride];
    ushort8 p3 = Pb[i + 3 * stride];

    f32x4 lo, hi;
#pragma unroll
    for (int e = 0; e < 8; ++e) {
        union { unsigned int u; float f; } c0, c1, c2, c3;
        c0.u = (unsigned int)p0[e] << 16;
        c1.u = (unsigned int)p1[e] << 16;
        c2.u = (unsigned int)p2[e] << 16;
        c3.u = (unsigned int)p3[e] << 16;
        float s = (c0.f + c1.f) + (c2.f + c3.f);
        if (e < 4) lo[e] = s; else hi[e - 4] = s;
    }
    out[i * 2]     = lo;
    out[i * 2 + 1] = hi;
}

// ---------------------------------------------------------------------------
extern "C" void kernel_launch(void* const* d_in, const int* in_sizes, int n_in,
                              void* d_out, int out_size, void* d_ws, size_t ws_size,
                              hipStream_t stream) {
    const float* x = (const float*)d_in[0];       // (4096, 1024) fp32
    const float* w = (const float*)d_in[1];       // (1024, 1024, 8) fp32
    float* out = (float*)d_out;                   // (4096, 1024) fp32

    const size_t offP  = (size_t)OUTF * KDIM * 2;              // Wbf: 16 MiB
    const size_t needP = offP + (size_t)KS * BATCH * OUTF * 2; // +32 MiB bf16 partials

    __hip_bfloat16* Wbf = (__hip_bfloat16*)d_ws;
    __hip_bfloat16* Pb  = (__hip_bfloat16*)((char*)d_ws + offP);
    const bool partials = (ws_size >= needP);

    kan_wconv<<<(OUTF * KDIM / 8) / 256, 256, 0, stream>>>((const f32x4*)w, (short8*)Wbf);

    const int grid = (BATCH / 256) * (OUTF / 256) * KS;     // 256
    if (partials) {
        kan_gemm<<<grid, 1024, 0, stream>>>(x, Wbf, Pb, out, 0);
        kan_reduce<<<(BATCH * OUTF / 8) / 256, 256, 0, stream>>>((const ushort8*)Pb, (f32x4*)out);
    } else {
        hipMemsetAsync(out, 0, (size_t)BATCH * OUTF * sizeof(float), stream);
        kan_gemm<<<grid, 1024, 0, stream>>>(x, Wbf, Pb, out, 1);
    }
}